// Round 7
// baseline (150.312 us; speedup 1.0000x reference)
//
#include <hip/hip_runtime.h>
#include <limits.h>

// Problem constants (fixed by setup_inputs):
//   xyz (B,N,3) f32, new_xyz (B,P,3) f32, features (B,C,N) f32
//   out = concat([grouped_xyz - center, grouped_features], ch) -> (B, 3+C, P, S)
#define BB 2
#define NN 16384
#define PP 4096
#define CC 64
#define SS 32
#define R2 0.01f
#define OUTCH (3 + CC)
#define GRES 10
#define NCELL 1000   // 10x10x10, cell size 0.1 == radius
#define BIN_REPS 4   // ATTRIBUTION: amplify bin cost so it surfaces in top-5
#define Q_REPS 3     // ATTRIBUTION: amplify query cost so it surfaces in top-5

__device__ __forceinline__ int cell_of(float v) {
  int q = (int)(v * 10.0f);  // v in [0,1): floor
  return q < 0 ? 0 : (q > GRES - 1 ? GRES - 1 : q);
}
__device__ __forceinline__ int cell_clamp_floor(float v) {
  int q = (int)floorf(v * 10.0f);
  return q < 0 ? 0 : (q > GRES - 1 ? GRES - 1 : q);
}

// --------------------------------------------------------------------------
// Fused binning (REPEATED x4 for attribution; each rep recomputes the same
// result; z0 asm barrier defeats cross-rep hoisting; barriers make the LDS
// counter reuse race-free). Emits CSR cellStart[] and sorted4[]=(x,y,z,idx).
// Within-cell order is atomic-arrival (nondeterministic) but downstream
// output depends only on the SET of in-ball indices (bitmap) => determinism.
// --------------------------------------------------------------------------
__global__ __launch_bounds__(1024) void bin_kernel(
    const float* __restrict__ xyz, int* __restrict__ cellStartG,
    float4* __restrict__ sorted4) {
  __shared__ int hist[NCELL];
  __shared__ int fill[NCELL];
  __shared__ int cstart[NCELL];
  __shared__ int wtot[16];
  const int b = blockIdx.x;
  const int t = threadIdx.x;
  const int lane = t & 63;
  const int w = t >> 6;
  const float* __restrict__ xb = xyz + (size_t)b * NN * 3;

  for (int rep = 0; rep < BIN_REPS; ++rep) {
    int z0 = 0;
    asm volatile("" : "+v"(z0));  // opaque zero: blocks cross-rep CSE/hoist

    if (t < NCELL) { hist[t] = 0; fill[t] = 0; }
    __syncthreads();

    int cells[16];
#pragma unroll
    for (int k = 0; k < 16; ++k) {
      const int i = t + k * 1024 + z0;
      const float x = xb[i * 3 + 0];
      const float y = xb[i * 3 + 1];
      const float z = xb[i * 3 + 2];
      const int c = (cell_of(z) * GRES + cell_of(y)) * GRES + cell_of(x);
      cells[k] = c;
      atomicAdd(&hist[c], 1);
    }
    __syncthreads();

    // exclusive scan over 1000 cells
    const int own = (t < NCELL) ? hist[t] : 0;
    int incl = own;
#pragma unroll
    for (int d = 1; d < 64; d <<= 1) {
      const int v = __shfl_up(incl, d);
      if (lane >= d) incl += v;
    }
    if (lane == 63) wtot[w] = incl;
    __syncthreads();
    int pre = 0;
#pragma unroll
    for (int k = 0; k < 16; ++k) pre += (k < w) ? wtot[k] : 0;
    const int excl = pre + incl - own;
    if (t < NCELL) {
      cstart[t] = excl;
      cellStartG[b * 1001 + t] = excl;
    }
    if (t == 0) cellStartG[b * 1001 + NCELL] = NN;
    __syncthreads();

#pragma unroll
    for (int k = 0; k < 16; ++k) {
      const int i = t + k * 1024 + z0;
      const float x = xb[i * 3 + 0];
      const float y = xb[i * 3 + 1];
      const float z = xb[i * 3 + 2];
      const int c = cells[k];
      const int r = atomicAdd(&fill[c], 1);
      float4 v;
      v.x = x; v.y = y; v.z = z; v.w = __int_as_float(i);
      sorted4[(size_t)b * NN + cstart[c] + r] = v;
    }
    __syncthreads();  // scatter done before next rep re-zeroes counters
  }
}

// --------------------------------------------------------------------------
// Ball query (standalone again; REPEATED x3 for attribution — cx/cy/cz pass
// through an asm identity each rep so the whole body is recomputed).
// NEW: candidate loop is software-pipelined 2-deep (prefetch chunk k+1 while
// testing chunk k) to cut the serial load->wait->test chain.
// Algorithm unchanged from the passing R5/R6 kernel: flattened <=9 CSR
// ranges, 16384-bit LDS bitmap (9-word padded stripes), popcount+shfl scan
// emitting the first SS in ascending original-index order. Box margin +1e-5
// only ADDs exactly-tested candidates; d2 matches numpy bit-exactly
// (fp contract off, (dx^2+dy^2)+dz^2 order).
// --------------------------------------------------------------------------
__global__ __launch_bounds__(256) void ball_query_grid(
    const float4* __restrict__ sorted4, const int* __restrict__ cellStart,
    const float* __restrict__ new_xyz, int* __restrict__ idx_out) {
#pragma clang fp contract(off)
  __shared__ unsigned bmAll[4 * 576];  // 4 waves x (512 words padded 64*9)
  const int widx = threadIdx.x >> 6;
  const int lane = threadIdx.x & 63;
  const int wave = blockIdx.x * 4 + widx;
  const int b = wave >> 12;  // PP = 4096
  unsigned* bm = bmAll + widx * 576;

  float cx = new_xyz[wave * 3 + 0];
  float cy = new_xyz[wave * 3 + 1];
  float cz = new_xyz[wave * 3 + 2];
  const float4* __restrict__ sb = sorted4 + (size_t)b * NN;
  const int* __restrict__ csb = cellStart + b * 1001;
  int* __restrict__ myout = idx_out + wave * SS;

  for (int rep = 0; rep < Q_REPS; ++rep) {
    asm volatile("" : "+v"(cx), "+v"(cy), "+v"(cz));  // identity; blocks CSE

#pragma unroll
    for (int k = 0; k < 9; ++k) bm[k * 64 + lane] = 0;

    const float mg = 0.1f + 1e-5f;
    const int lox = cell_clamp_floor(cx - mg), hix = cell_clamp_floor(cx + mg);
    const int loy = cell_clamp_floor(cy - mg), hiy = cell_clamp_floor(cy + mg);
    const int loz = cell_clamp_floor(cz - mg), hiz = cell_clamp_floor(cz + mg);
    const int nx = hix - lox + 1;
    const int ny = hiy - loy + 1;
    const int nz = hiz - loz + 1;
    const int nr = nz * ny;  // 1..9 row-ranges

    int s_l = 0, len_l = 0;
    if (lane < nr) {
      int zi, yi;
      if (ny == 1) { zi = lane; yi = 0; }
      else if (ny == 2) { zi = lane >> 1; yi = lane & 1; }
      else { zi = (lane * 11) >> 5; yi = lane - zi * 3; }  // lane/3, lane<9
      const int c0 = ((loz + zi) * GRES + (loy + yi)) * GRES + lox;
      s_l = csb[c0];
      len_l = csb[c0 + nx] - s_l;
    }
    int incl = len_l;
#pragma unroll
    for (int d = 1; d <= 8; d <<= 1) {
      const int v = __shfl_up(incl, d);
      if (lane >= d) incl += v;
    }
    const int T = __shfl(incl, nr - 1);  // total candidates
    const int Lx = incl - len_l;

    int Lk[9], Sk[9];
#pragma unroll
    for (int k = 0; k < 9; ++k) {  // Lk[k] == T for k >= nr
      Lk[k] = __shfl(Lx, k);
      Sk[k] = __shfl(s_l, k);
    }

    auto flat_load = [&](int g) -> float4 {
      int L = Lk[0], S = Sk[0];
#pragma unroll
      for (int k = 1; k < 9; ++k) {
        const bool cge = g >= Lk[k];
        L = cge ? Lk[k] : L;
        S = cge ? Sk[k] : S;
      }
      return sb[S + (g - L)];
    };

    // 2-deep pipelined candidate loop
    const int nIt = (T + 63) >> 6;
    float4 cur = {};
    if (lane < T) cur = flat_load(lane);
    for (int it = 0; it < nIt; ++it) {
      float4 nxt = cur;
      const int gn = (it + 1) * 64 + lane;
      if (gn < T) nxt = flat_load(gn);  // prefetch next chunk
      const int g = it * 64 + lane;
      if (g < T) {
        const float dx = cx - cur.x;
        const float dy = cy - cur.y;
        const float dz = cz - cur.z;
        const float a = dx * dx + dy * dy;
        const float d2 = a + dz * dz;
        if (d2 < R2) {
          const int orig = __float_as_int(cur.w);
          const int wi = orig >> 5;  // word 0..511
          atomicOr(&bm[(wi >> 3) * 9 + (wi & 7)], 1u << (orig & 31));
        }
      }
      cur = nxt;
    }
    __threadfence_block();  // drain LDS atomics before the scan reads

    // Scan: lane l owns words [8l,8l+8) = orig indices [256l, 256l+256).
    unsigned wv[8];
    int c = 0;
    int fi = INT_MAX;
#pragma unroll
    for (int k = 0; k < 8; ++k) {
      wv[k] = bm[lane * 9 + k];
      c += (int)__popc(wv[k]);
      if (fi == INT_MAX && wv[k])
        fi = lane * 256 + k * 32 + (int)__builtin_ctz(wv[k]);
    }

    int incl2 = c;
#pragma unroll
    for (int d = 1; d < 64; d <<= 1) {
      const int t = __shfl_up(incl2, d);
      if (lane >= d) incl2 += t;
    }
    const int E = incl2 - c;
    const int total = __shfl(incl2, 63);

    const unsigned long long nb = __ballot(c > 0);
    int fc = 0;
    if (nb) fc = __shfl(fi, (int)__builtin_ctzll(nb));

    int s = E;
    if (s < SS) {
#pragma unroll
      for (int k = 0; k < 8; ++k) {
        unsigned ww = wv[k];
        while (ww && s < SS) {
          const int bpos = (int)__builtin_ctz(ww);
          ww &= ww - 1;
          myout[s++] = lane * 256 + k * 32 + bpos;
        }
        if (s >= SS) break;
      }
    }
    for (int s2 = total + lane; s2 < SS; s2 += 64) myout[s2] = fc;
  }
}

// --------------------------------------------------------------------------
// Transpose features (B,C,N) -> (B,N,C): gathers then read full 256B rows.
// --------------------------------------------------------------------------
__global__ __launch_bounds__(256) void transpose_feat_kernel(
    const float* __restrict__ feat, float* __restrict__ featT) {
  __shared__ float tile[64][65];
  const int n0 = blockIdx.x * 64;
  const int b = blockIdx.y;
  const int jn = threadIdx.x & 63;
  const int g4 = threadIdx.x >> 6;

  const float* fb = feat + (size_t)b * CC * NN;
#pragma unroll
  for (int k = 0; k < 16; ++k) {
    const int c = g4 * 16 + k;
    tile[c][jn] = fb[(size_t)c * NN + n0 + jn];
  }
  __syncthreads();
  float* ft = featT + ((size_t)b * NN + n0) * CC;
#pragma unroll
  for (int k = 0; k < 16; ++k) {
    const int j = g4 * 16 + k;
    ft[(size_t)j * CC + jn] = tile[jn][j];
  }
}

// --------------------------------------------------------------------------
// Gather + group via LDS staging (TILE=128 samples/block), coalesced stores.
// --------------------------------------------------------------------------
#define TILE 128
__global__ __launch_bounds__(256) void group_kernel_t(
    const float* __restrict__ xyz, const float* __restrict__ new_xyz,
    const float* __restrict__ featT, const int* __restrict__ idx,
    float* __restrict__ out) {
  __shared__ float lds[TILE * 65];
  const int base = blockIdx.x * TILE;
  const int b = base >> 17;  // P*S = 2^17
  const int t = threadIdx.x;
  const size_t PS = (size_t)PP * SS;

  const float4* ftb = (const float4*)(featT + (size_t)b * NN * CC);
#pragma unroll
  for (int k = 0; k < 8; ++k) {
    const int u = k * 256 + t;
    const int r = u >> 4;
    const int q = u & 15;
    const int v = idx[base + r];
    const float4 val = ftb[(size_t)v * 16 + q];
    float* dst = &lds[r * 65 + q * 4];
    dst[0] = val.x; dst[1] = val.y; dst[2] = val.z; dst[3] = val.w;
  }
  __syncthreads();

  if (t < TILE) {
    const int g = base + t;
    const int v = idx[g];
    const int p = (g >> 5) & (PP - 1);
    const float* xr = xyz + ((size_t)b * NN + v) * 3;
    const float* cr = new_xyz + (size_t)(b * PP + p) * 3;
    const size_t ob = (size_t)b * OUTCH * PS + ((size_t)g & (PS - 1));
    out[ob + 0 * PS] = xr[0] - cr[0];
    out[ob + 1 * PS] = xr[1] - cr[1];
    out[ob + 2 * PS] = xr[2] - cr[2];
  }

  float* ob3 = out + (size_t)b * OUTCH * PS + 3 * PS + ((size_t)base & (PS - 1));
#pragma unroll
  for (int k = 0; k < 32; ++k) {
    const int u = k * 256 + t;
    const int c = u >> 7;
    const int r = u & 127;
    ob3[(size_t)c * PS + r] = lds[r * 65 + c];
  }
}

extern "C" void kernel_launch(void* const* d_in, const int* in_sizes, int n_in,
                              void* d_out, int out_size, void* d_ws, size_t ws_size,
                              hipStream_t stream) {
  const float* xyz = (const float*)d_in[0];
  const float* new_xyz = (const float*)d_in[1];
  const float* feat = (const float*)d_in[2];
  float* out = (float*)d_out;

  // ws layout: [idx 1MB][ovl: featT 8.39MB | sorted4 0.5MB + cellStart 8KB]
  // (bin+query finish before transpose overwrites ovl -> alias is safe).
  const size_t idxBytes = (size_t)BB * PP * SS * sizeof(int);
  int* idx = (int*)d_ws;
  char* ovl = (char*)d_ws + idxBytes;
  float* featT = (float*)ovl;
  float4* sorted4 = (float4*)ovl;
  int* cellStart = (int*)(ovl + (size_t)BB * NN * sizeof(float4));

  bin_kernel<<<BB, 1024, 0, stream>>>(xyz, cellStart, sorted4);
  ball_query_grid<<<(BB * PP) / 4, 256, 0, stream>>>(sorted4, cellStart, new_xyz, idx);
  transpose_feat_kernel<<<dim3(NN / 64, BB), 256, 0, stream>>>(feat, featT);
  group_kernel_t<<<(BB * PP * SS) / TILE, 256, 0, stream>>>(xyz, new_xyz, featT,
                                                            idx, out);
}

// Round 8
// 66.273 us; speedup vs baseline: 2.2681x; 2.2681x over previous
//
#include <hip/hip_runtime.h>
#include <limits.h>

// Problem constants (fixed by setup_inputs):
//   xyz (B,N,3) f32, new_xyz (B,P,3) f32, features (B,C,N) f32
//   out = concat([grouped_xyz - center, grouped_features], ch) -> (B, 3+C, P, S)
#define BB 2
#define NN 16384
#define PP 4096
#define CC 64
#define SS 32
#define R2 0.01f
#define OUTCH (3 + CC)
#define GRES 10
#define NCELL 1000  // 10x10x10, cell size 0.1 == radius
#define TILE 128    // samples per block in the fused kernel (4 queries x 32)

__device__ __forceinline__ int cell_of(float v) {
  int q = (int)(v * 10.0f);  // v in [0,1): floor
  return q < 0 ? 0 : (q > GRES - 1 ? GRES - 1 : q);
}
__device__ __forceinline__ int cell_clamp_floor(float v) {
  int q = (int)floorf(v * 10.0f);
  return q < 0 ? 0 : (q > GRES - 1 ? GRES - 1 : q);
}

// --------------------------------------------------------------------------
// Grid-parallel binning chain (R7 showed the fused 2-block version ran at
// 0.32% occupancy, ~16 us). hist and scatter use 128 blocks; scan is tiny.
// Within-cell order is atomic-arrival (nondeterministic) but downstream
// output depends only on the SET of in-ball indices (bitmap) => determinism.
// --------------------------------------------------------------------------
__global__ __launch_bounds__(256) void hist_kernel(const float* __restrict__ xyz,
                                                   int* __restrict__ hist) {
  const int i = blockIdx.x * 256 + threadIdx.x;  // [0, BB*NN)
  const int b = i >> 14;
  const float* p = xyz + (size_t)i * 3;
  const int c = (cell_of(p[2]) * GRES + cell_of(p[1])) * GRES + cell_of(p[0]);
  atomicAdd(hist + b * NCELL + c, 1);
}

__global__ __launch_bounds__(1024) void scan_kernel(const int* __restrict__ hist,
                                                    int* __restrict__ cellStart) {
  __shared__ int sm[1024];
  const int b = blockIdx.x;
  const int t = threadIdx.x;
  const int own = (t < NCELL) ? hist[b * NCELL + t] : 0;
  sm[t] = own;
  __syncthreads();
  for (int off = 1; off < 1024; off <<= 1) {
    const int v = (t >= off) ? sm[t - off] : 0;
    __syncthreads();
    sm[t] += v;
    __syncthreads();
  }
  if (t < NCELL) cellStart[b * 1001 + t] = sm[t] - own;
  if (t == NCELL - 1) cellStart[b * 1001 + NCELL] = sm[t];
}

__global__ __launch_bounds__(256) void scatter_kernel(
    const float* __restrict__ xyz, const int* __restrict__ cellStart,
    int* __restrict__ fill, float4* __restrict__ sorted4) {
  const int i = blockIdx.x * 256 + threadIdx.x;  // [0, BB*NN)
  const int b = i >> 14;
  const float* p = xyz + (size_t)i * 3;
  const float x = p[0], y = p[1], z = p[2];
  const int c = (cell_of(z) * GRES + cell_of(y)) * GRES + cell_of(x);
  const int r = atomicAdd(fill + b * NCELL + c, 1);
  const int pos = cellStart[b * 1001 + c] + r;
  float4 v;
  v.x = x; v.y = y; v.z = z; v.w = __int_as_float(i & (NN - 1));
  sorted4[(size_t)b * NN + pos] = v;
}

// --------------------------------------------------------------------------
// Transpose features (B,C,N) -> (B,N,C): gathers then read full 256B rows.
// --------------------------------------------------------------------------
__global__ __launch_bounds__(256) void transpose_feat_kernel(
    const float* __restrict__ feat, float* __restrict__ featT) {
  __shared__ float tile[64][65];
  const int n0 = blockIdx.x * 64;
  const int b = blockIdx.y;
  const int jn = threadIdx.x & 63;
  const int g4 = threadIdx.x >> 6;

  const float* fb = feat + (size_t)b * CC * NN;
#pragma unroll
  for (int k = 0; k < 16; ++k) {
    const int c = g4 * 16 + k;
    tile[c][jn] = fb[(size_t)c * NN + n0 + jn];
  }
  __syncthreads();
  float* ft = featT + ((size_t)b * NN + n0) * CC;
#pragma unroll
  for (int k = 0; k < 16; ++k) {
    const int j = g4 * 16 + k;
    ft[(size_t)j * CC + jn] = tile[jn][j];
  }
}

// --------------------------------------------------------------------------
// FUSED query + group. One block = 4 query-waves = TILE(128) samples.
//
// Phase Q (per wave): grid ball query with SPHERE-TIGHT row ranges: for each
// of the <=9 (z,y) rows in the ball's cell box, the owning lane computes the
// row's min distance to the center and solves dx^2 < reff^2 - dymin^2 -
// dzmin^2 for a per-row x-cell span (rows the sphere cannot reach get len 0).
// Conservative: reff = r + 1e-5 >> all fp rounding here, and every surviving
// candidate still takes the EXACT d2 < R2 test (fp contract off, numpy
// (dx^2+dy^2)+dz^2 order) => identical in-ball set, absmax 0.
// Ranges are flattened via shfl-scan into one candidate space traversed in
// fully-packed 64-lane chunks (2-deep pipelined loads). In-ball indices are
// marked in a per-wave 16384-bit LDS bitmap (9-word padded stripes =>
// conflict-free); popcount + shfl-scan emits the first SS in ascending
// original-index order into LDS idxsm.
//
// Phase G: stage 128 gathered featT rows (256B each) into LDS (stride 65 =>
// conflict-free), write xyz-diff channels, channel-major coalesced stores.
// --------------------------------------------------------------------------
__global__ __launch_bounds__(256) void query_group_kernel(
    const float4* __restrict__ sorted4, const int* __restrict__ cellStart,
    const float* __restrict__ new_xyz, const float* __restrict__ xyz,
    const float* __restrict__ featT, float* __restrict__ out) {
#pragma clang fp contract(off)
  __shared__ float smem[TILE * 65];  // 33280 B; bitmap phase uses first 9216 B
  __shared__ int idxsm[TILE];
  const int widx = threadIdx.x >> 6;
  const int lane = threadIdx.x & 63;
  const int wave = blockIdx.x * 4 + widx;  // global query id
  const int b = wave >> 12;                // PP = 4096
  unsigned* bm = (unsigned*)smem + widx * 576;  // this wave's 512+pad words
  int* myout = idxsm + widx * SS;

  const float cx = new_xyz[wave * 3 + 0];
  const float cy = new_xyz[wave * 3 + 1];
  const float cz = new_xyz[wave * 3 + 2];
  const float4* __restrict__ sb = sorted4 + (size_t)b * NN;
  const int* __restrict__ csb = cellStart + b * 1001;

#pragma unroll
  for (int k = 0; k < 9; ++k) bm[k * 64 + lane] = 0;

  const float mg = 0.1f + 1e-5f;
  const int loy = cell_clamp_floor(cy - mg), hiy = cell_clamp_floor(cy + mg);
  const int loz = cell_clamp_floor(cz - mg), hiz = cell_clamp_floor(cz + mg);
  const int ny = hiy - loy + 1;
  const int nz = hiz - loz + 1;
  const int nr = nz * ny;  // 1..9 (z,y) rows

  // lanes 0..nr-1: sphere-tight x-range + CSR bounds for their row
  int s_l = 0, len_l = 0;
  if (lane < nr) {
    int zi, yi;
    if (ny == 1) { zi = lane; yi = 0; }
    else if (ny == 2) { zi = lane >> 1; yi = lane & 1; }
    else { zi = (lane * 11) >> 5; yi = lane - zi * 3; }  // lane/3, lane<9
    const int zc = loz + zi, yc = loy + yi;
    const float y0 = yc * 0.1f, z0 = zc * 0.1f;
    const float dymin = fmaxf(fmaxf(y0 - cy, cy - (y0 + 0.1f)), 0.0f);
    const float dzmin = fmaxf(fmaxf(z0 - cz, cz - (z0 + 0.1f)), 0.0f);
    const float rem = mg * mg - dymin * dymin - dzmin * dzmin;
    if (rem > 0.0f) {
      const float dxa = sqrtf(rem) * 1.0000002f + 1e-7f;  // round-up guard
      const int lxr = cell_clamp_floor(cx - dxa);
      const int hxr = cell_clamp_floor(cx + dxa);
      const int c0 = (zc * GRES + yc) * GRES + lxr;
      s_l = csb[c0];
      len_l = csb[c0 + (hxr - lxr + 1)] - s_l;
    }
  }
  int incl = len_l;
#pragma unroll
  for (int d = 1; d <= 8; d <<= 1) {  // prefix correct for lanes < 16 >= nr
    const int v = __shfl_up(incl, d);
    if (lane >= d) incl += v;
  }
  const int T = __shfl(incl, nr - 1);  // total candidates
  const int Lx = incl - len_l;         // exclusive offset of this range

  int Lk[9], Sk[9];
#pragma unroll
  for (int k = 0; k < 9; ++k) {  // Lk[k] == T for k >= nr
    Lk[k] = __shfl(Lx, k);
    Sk[k] = __shfl(s_l, k);
  }

  auto flat_load = [&](int g) -> float4 {
    int L = Lk[0], S = Sk[0];
#pragma unroll
    for (int k = 1; k < 9; ++k) {
      const bool cge = g >= Lk[k];
      L = cge ? Lk[k] : L;
      S = cge ? Sk[k] : S;
    }
    return sb[S + (g - L)];
  };

  // 2-deep pipelined candidate loop
  const int nIt = (T + 63) >> 6;
  float4 cur = {};
  if (lane < T) cur = flat_load(lane);
  for (int it = 0; it < nIt; ++it) {
    float4 nxt = cur;
    const int gn = (it + 1) * 64 + lane;
    if (gn < T) nxt = flat_load(gn);  // prefetch next chunk
    const int g = it * 64 + lane;
    if (g < T) {
      const float dx = cx - cur.x;
      const float dy = cy - cur.y;
      const float dz = cz - cur.z;
      const float a = dx * dx + dy * dy;
      const float d2 = a + dz * dz;
      if (d2 < R2) {
        const int orig = __float_as_int(cur.w);
        const int wi = orig >> 5;  // word 0..511
        atomicOr(&bm[(wi >> 3) * 9 + (wi & 7)], 1u << (orig & 31));
      }
    }
    cur = nxt;
  }
  __threadfence_block();  // drain LDS atomics before the scan reads

  // Scan: lane l owns words [8l,8l+8) = orig indices [256l, 256l+256).
  unsigned wv[8];
  int c = 0;
  int fi = INT_MAX;
#pragma unroll
  for (int k = 0; k < 8; ++k) {
    wv[k] = bm[lane * 9 + k];
    c += (int)__popc(wv[k]);
    if (fi == INT_MAX && wv[k])
      fi = lane * 256 + k * 32 + (int)__builtin_ctz(wv[k]);
  }

  int incl2 = c;
#pragma unroll
  for (int d = 1; d < 64; d <<= 1) {
    const int t = __shfl_up(incl2, d);
    if (lane >= d) incl2 += t;
  }
  const int E = incl2 - c;              // exclusive prefix
  const int total = __shfl(incl2, 63);  // wave total in-ball count

  const unsigned long long nb = __ballot(c > 0);
  int fc = 0;
  if (nb) fc = __shfl(fi, (int)__builtin_ctzll(nb));

  int s = E;
  if (s < SS) {
#pragma unroll
    for (int k = 0; k < 8; ++k) {
      unsigned ww = wv[k];
      while (ww && s < SS) {
        const int bpos = (int)__builtin_ctz(ww);
        ww &= ww - 1;
        myout[s++] = lane * 256 + k * 32 + bpos;
      }
      if (s >= SS) break;
    }
  }
  for (int s2 = total + lane; s2 < SS; s2 += 64) myout[s2] = fc;

  __syncthreads();  // idxsm complete for all 4 waves; bitmap LDS now dead

  // ---------------- Phase G: gather + group ------------------------------
  const int base = blockIdx.x * TILE;
  const int t = threadIdx.x;
  const size_t PS = (size_t)PP * SS;

  const float4* ftb = (const float4*)(featT + (size_t)b * NN * CC);
#pragma unroll
  for (int k = 0; k < 8; ++k) {
    const int u = k * 256 + t;  // [0, 2048)
    const int r = u >> 4;       // sample row 0..127
    const int q = u & 15;       // float4 within row
    const int v = idxsm[r];
    const float4 val = ftb[(size_t)v * 16 + q];
    float* dst = &smem[r * 65 + q * 4];
    dst[0] = val.x; dst[1] = val.y; dst[2] = val.z; dst[3] = val.w;
  }
  __syncthreads();

  if (t < TILE) {
    const int g = base + t;
    const int v = idxsm[t];
    const int p = (g >> 5) & (PP - 1);
    const float* xr = xyz + ((size_t)b * NN + v) * 3;
    const float* cr = new_xyz + (size_t)(b * PP + p) * 3;
    const size_t ob = (size_t)b * OUTCH * PS + ((size_t)g & (PS - 1));
    out[ob + 0 * PS] = xr[0] - cr[0];
    out[ob + 1 * PS] = xr[1] - cr[1];
    out[ob + 2 * PS] = xr[2] - cr[2];
  }

  float* ob3 = out + (size_t)b * OUTCH * PS + 3 * PS + ((size_t)base & (PS - 1));
#pragma unroll
  for (int k = 0; k < 32; ++k) {
    const int u = k * 256 + t;  // [0, 8192)
    const int c2 = u >> 7;      // channel 0..63
    const int r = u & 127;      // row 0..127
    ob3[(size_t)c2 * PS + r] = smem[r * 65 + c2];
  }
}

extern "C" void kernel_launch(void* const* d_in, const int* in_sizes, int n_in,
                              void* d_out, int out_size, void* d_ws, size_t ws_size,
                              hipStream_t stream) {
  const float* xyz = (const float*)d_in[0];
  const float* new_xyz = (const float*)d_in[1];
  const float* feat = (const float*)d_in[2];
  float* out = (float*)d_out;

  // ws layout (featT and grid structures live simultaneously => disjoint):
  //   [featT 8.39MB][sorted4 0.5MB][cellStart 8008B][hist 8000B][fill 8000B]
  float* featT = (float*)d_ws;
  char* p = (char*)d_ws + (size_t)BB * NN * CC * sizeof(float);
  float4* sorted4 = (float4*)p;
  p += (size_t)BB * NN * sizeof(float4);
  int* cellStart = (int*)p;
  p += (size_t)BB * 1001 * sizeof(int);
  int* hist = (int*)p;
  int* fill = hist + BB * NCELL;

  // zero hist+fill (contiguous 16000 B) every call — graph-capturable node
  hipMemsetAsync(hist, 0, (size_t)2 * BB * NCELL * sizeof(int), stream);
  hist_kernel<<<(BB * NN) / 256, 256, 0, stream>>>(xyz, hist);
  scan_kernel<<<BB, 1024, 0, stream>>>(hist, cellStart);
  scatter_kernel<<<(BB * NN) / 256, 256, 0, stream>>>(xyz, cellStart, fill, sorted4);
  transpose_feat_kernel<<<dim3(NN / 64, BB), 256, 0, stream>>>(feat, featT);
  query_group_kernel<<<(BB * PP) / 4, 256, 0, stream>>>(sorted4, cellStart,
                                                        new_xyz, xyz, featT, out);
}

// Round 9
// 64.072 us; speedup vs baseline: 2.3460x; 1.0343x over previous
//
#include <hip/hip_runtime.h>
#include <limits.h>

// Problem constants (fixed by setup_inputs):
//   xyz (B,N,3) f32, new_xyz (B,P,3) f32, features (B,C,N) f32
//   out = concat([grouped_xyz - center, grouped_features], ch) -> (B, 3+C, P, S)
#define BB 2
#define NN 16384
#define PP 4096
#define CC 64
#define SS 32
#define R2 0.01f
#define OUTCH (3 + CC)
#define GRES 10
#define NCELL 1000   // 10x10x10, cell size 0.1 == radius
#define TILE 128     // samples per block in the fused kernel (4 queries x 32)
#define BINBLK 128   // bin_all blocks (64 per batch) — co-resident on 256 CUs

__device__ __forceinline__ int cell_of(float v) {
  int q = (int)(v * 10.0f);  // v in [0,1): floor
  return q < 0 ? 0 : (q > GRES - 1 ? GRES - 1 : q);
}
__device__ __forceinline__ int cell_clamp_floor(float v) {
  int q = (int)floorf(v * 10.0f);
  return q < 0 ? 0 : (q > GRES - 1 ? GRES - 1 : q);
}

// --------------------------------------------------------------------------
// Transpose features (B,C,N) -> (B,N,C). Block (0,0) additionally zeroes the
// hist/fill/done scratch (4008 ints) — replaces the pathological 45 us
// hipMemsetAsync fill node observed in R8, and (stream-ordered) guarantees
// bin_all's counters and barrier flag are zeroed on EVERY call (replay-safe).
// --------------------------------------------------------------------------
__global__ __launch_bounds__(256) void transpose_feat_kernel(
    const float* __restrict__ feat, float* __restrict__ featT,
    int* __restrict__ zeroRegion) {
  __shared__ float tile[64][65];
  const int n0 = blockIdx.x * 64;
  const int b = blockIdx.y;
  const int jn = threadIdx.x & 63;
  const int g4 = threadIdx.x >> 6;

  if (blockIdx.x == 0 && blockIdx.y == 0) {
    for (int k = threadIdx.x; k < 2 * BB * NCELL + 8; k += 256) zeroRegion[k] = 0;
  }

  const float* fb = feat + (size_t)b * CC * NN;
#pragma unroll
  for (int k = 0; k < 16; ++k) {
    const int c = g4 * 16 + k;
    tile[c][jn] = fb[(size_t)c * NN + n0 + jn];
  }
  __syncthreads();
  float* ft = featT + ((size_t)b * NN + n0) * CC;
#pragma unroll
  for (int k = 0; k < 16; ++k) {
    const int j = g4 * 16 + k;
    ft[(size_t)j * CC + jn] = tile[jn][j];
  }
}

// --------------------------------------------------------------------------
// ONE-DISPATCH binning. 128 blocks (64/batch, 256 pts each, 1 pt/thread).
// Phase A: global-atomic histogram (histG pre-zeroed by transpose).
// Grid barrier: threadfence + arrive-count + spin (device-scope atomics;
// 128 small blocks are trivially co-resident on 256 CUs => no deadlock).
// Phase B: EVERY block redundantly scans its batch's 1000-cell histogram
// into a private LDS cellStart copy (250 thr x 4 cells, shfl-scan) — no
// second barrier needed. First block of each batch publishes it globally.
// Phase C: scatter with global fill atomics (fillG pre-zeroed).
// Within-cell order is atomic-arrival (nondeterministic) but downstream
// output depends only on the SET of in-ball indices (bitmap) => determinism.
// --------------------------------------------------------------------------
__global__ __launch_bounds__(256) void bin_all_kernel(
    const float* __restrict__ xyz, int* __restrict__ histG,
    int* __restrict__ fillG, int* __restrict__ doneG,
    int* __restrict__ cellStartG, float4* __restrict__ sorted4) {
  __shared__ int cstart[NCELL];
  __shared__ int wsum[4];
  const int blk = blockIdx.x;   // 0..127
  const int b = blk >> 6;       // 64 blocks per batch
  const int t = threadIdx.x;
  const int lane = t & 63;
  const int w = t >> 6;
  const int i = (blk & 63) * 256 + t;  // point index within batch

  // ---- phase A: histogram ----
  const float* p = xyz + ((size_t)b * NN + i) * 3;
  const float x = p[0], y = p[1], z = p[2];
  const int c = (cell_of(z) * GRES + cell_of(y)) * GRES + cell_of(x);
  atomicAdd(histG + b * NCELL + c, 1);

  // ---- grid barrier ----
  __threadfence();   // make my hist add globally visible before arriving
  __syncthreads();   // whole block done with phase A
  if (t == 0) {
    atomicAdd(doneG, 1);
    while (__hip_atomic_load(doneG, __ATOMIC_ACQUIRE,
                             __HIP_MEMORY_SCOPE_AGENT) < BINBLK) {
    }
  }
  __syncthreads();

  // ---- phase B: redundant per-block scan of this batch's histogram ----
  int v0 = 0, v1 = 0, v2 = 0, v3 = 0, s = 0;
  if (t < 250) {  // 250 threads x 4 cells = 1000
    const int base = b * NCELL + t * 4;
    v0 = __hip_atomic_load(histG + base + 0, __ATOMIC_RELAXED, __HIP_MEMORY_SCOPE_AGENT);
    v1 = __hip_atomic_load(histG + base + 1, __ATOMIC_RELAXED, __HIP_MEMORY_SCOPE_AGENT);
    v2 = __hip_atomic_load(histG + base + 2, __ATOMIC_RELAXED, __HIP_MEMORY_SCOPE_AGENT);
    v3 = __hip_atomic_load(histG + base + 3, __ATOMIC_RELAXED, __HIP_MEMORY_SCOPE_AGENT);
    s = v0 + v1 + v2 + v3;
  }
  int incl = s;
#pragma unroll
  for (int d = 1; d < 64; d <<= 1) {
    const int u = __shfl_up(incl, d);
    if (lane >= d) incl += u;
  }
  if (lane == 63) wsum[w] = incl;
  __syncthreads();
  int pre = 0;
#pragma unroll
  for (int k = 0; k < 4; ++k) pre += (k < w) ? wsum[k] : 0;
  if (t < 250) {
    int run = pre + incl - s;  // exclusive start of cell 4t
    cstart[t * 4 + 0] = run; run += v0;
    cstart[t * 4 + 1] = run; run += v1;
    cstart[t * 4 + 2] = run; run += v2;
    cstart[t * 4 + 3] = run;
  }
  __syncthreads();

  // publish cellStart once per batch (for the query kernel)
  if ((blk & 63) == 0) {
    if (t < 250) {
#pragma unroll
      for (int k = 0; k < 4; ++k)
        cellStartG[b * 1001 + t * 4 + k] = cstart[t * 4 + k];
    }
    if (t == 0) cellStartG[b * 1001 + NCELL] = NN;
  }

  // ---- phase C: scatter ----
  const int r = atomicAdd(fillG + b * NCELL + c, 1);
  const int pos = cstart[c] + r;
  float4 vv;
  vv.x = x; vv.y = y; vv.z = z; vv.w = __int_as_float(i);
  sorted4[(size_t)b * NN + pos] = vv;
}

// --------------------------------------------------------------------------
// FUSED query + group (byte-identical algorithm to the passing R8 kernel).
// Phase Q: grid ball query, sphere-tight per-row x-ranges, flattened via
// shfl-scan, 2-deep pipelined candidate loop, per-wave 16384-bit LDS bitmap
// (9-word padded stripes), popcount+shfl-scan emits first SS ascending.
// Conservative margins only ADD exactly-tested candidates; d2 matches numpy
// bit-exactly (fp contract off, (dx^2+dy^2)+dz^2 order) => absmax 0.
// Phase G: stage 128 gathered featT rows into LDS, coalesced stores.
// --------------------------------------------------------------------------
__global__ __launch_bounds__(256) void query_group_kernel(
    const float4* __restrict__ sorted4, const int* __restrict__ cellStart,
    const float* __restrict__ new_xyz, const float* __restrict__ xyz,
    const float* __restrict__ featT, float* __restrict__ out) {
#pragma clang fp contract(off)
  __shared__ float smem[TILE * 65];  // 33280 B; bitmap phase uses first 9216 B
  __shared__ int idxsm[TILE];
  const int widx = threadIdx.x >> 6;
  const int lane = threadIdx.x & 63;
  const int wave = blockIdx.x * 4 + widx;  // global query id
  const int b = wave >> 12;                // PP = 4096
  unsigned* bm = (unsigned*)smem + widx * 576;  // this wave's 512+pad words
  int* myout = idxsm + widx * SS;

  const float cx = new_xyz[wave * 3 + 0];
  const float cy = new_xyz[wave * 3 + 1];
  const float cz = new_xyz[wave * 3 + 2];
  const float4* __restrict__ sb = sorted4 + (size_t)b * NN;
  const int* __restrict__ csb = cellStart + b * 1001;

#pragma unroll
  for (int k = 0; k < 9; ++k) bm[k * 64 + lane] = 0;

  const float mg = 0.1f + 1e-5f;
  const int loy = cell_clamp_floor(cy - mg), hiy = cell_clamp_floor(cy + mg);
  const int loz = cell_clamp_floor(cz - mg), hiz = cell_clamp_floor(cz + mg);
  const int ny = hiy - loy + 1;
  const int nz = hiz - loz + 1;
  const int nr = nz * ny;  // 1..9 (z,y) rows

  // lanes 0..nr-1: sphere-tight x-range + CSR bounds for their row
  int s_l = 0, len_l = 0;
  if (lane < nr) {
    int zi, yi;
    if (ny == 1) { zi = lane; yi = 0; }
    else if (ny == 2) { zi = lane >> 1; yi = lane & 1; }
    else { zi = (lane * 11) >> 5; yi = lane - zi * 3; }  // lane/3, lane<9
    const int zc = loz + zi, yc = loy + yi;
    const float y0 = yc * 0.1f, z0 = zc * 0.1f;
    const float dymin = fmaxf(fmaxf(y0 - cy, cy - (y0 + 0.1f)), 0.0f);
    const float dzmin = fmaxf(fmaxf(z0 - cz, cz - (z0 + 0.1f)), 0.0f);
    const float rem = mg * mg - dymin * dymin - dzmin * dzmin;
    if (rem > 0.0f) {
      const float dxa = sqrtf(rem) * 1.0000002f + 1e-7f;  // round-up guard
      const int lxr = cell_clamp_floor(cx - dxa);
      const int hxr = cell_clamp_floor(cx + dxa);
      const int c0 = (zc * GRES + yc) * GRES + lxr;
      s_l = csb[c0];
      len_l = csb[c0 + (hxr - lxr + 1)] - s_l;
    }
  }
  int incl = len_l;
#pragma unroll
  for (int d = 1; d <= 8; d <<= 1) {  // prefix correct for lanes < 16 >= nr
    const int v = __shfl_up(incl, d);
    if (lane >= d) incl += v;
  }
  const int T = __shfl(incl, nr - 1);  // total candidates
  const int Lx = incl - len_l;         // exclusive offset of this range

  int Lk[9], Sk[9];
#pragma unroll
  for (int k = 0; k < 9; ++k) {  // Lk[k] == T for k >= nr
    Lk[k] = __shfl(Lx, k);
    Sk[k] = __shfl(s_l, k);
  }

  auto flat_load = [&](int g) -> float4 {
    int L = Lk[0], S = Sk[0];
#pragma unroll
    for (int k = 1; k < 9; ++k) {
      const bool cge = g >= Lk[k];
      L = cge ? Lk[k] : L;
      S = cge ? Sk[k] : S;
    }
    return sb[S + (g - L)];
  };

  // 2-deep pipelined candidate loop
  const int nIt = (T + 63) >> 6;
  float4 cur = {};
  if (lane < T) cur = flat_load(lane);
  for (int it = 0; it < nIt; ++it) {
    float4 nxt = cur;
    const int gn = (it + 1) * 64 + lane;
    if (gn < T) nxt = flat_load(gn);  // prefetch next chunk
    const int g = it * 64 + lane;
    if (g < T) {
      const float dx = cx - cur.x;
      const float dy = cy - cur.y;
      const float dz = cz - cur.z;
      const float a = dx * dx + dy * dy;
      const float d2 = a + dz * dz;
      if (d2 < R2) {
        const int orig = __float_as_int(cur.w);
        const int wi = orig >> 5;  // word 0..511
        atomicOr(&bm[(wi >> 3) * 9 + (wi & 7)], 1u << (orig & 31));
      }
    }
    cur = nxt;
  }
  __threadfence_block();  // drain LDS atomics before the scan reads

  // Scan: lane l owns words [8l,8l+8) = orig indices [256l, 256l+256).
  unsigned wv[8];
  int c = 0;
  int fi = INT_MAX;
#pragma unroll
  for (int k = 0; k < 8; ++k) {
    wv[k] = bm[lane * 9 + k];
    c += (int)__popc(wv[k]);
    if (fi == INT_MAX && wv[k])
      fi = lane * 256 + k * 32 + (int)__builtin_ctz(wv[k]);
  }

  int incl2 = c;
#pragma unroll
  for (int d = 1; d < 64; d <<= 1) {
    const int t = __shfl_up(incl2, d);
    if (lane >= d) incl2 += t;
  }
  const int E = incl2 - c;              // exclusive prefix
  const int total = __shfl(incl2, 63);  // wave total in-ball count

  const unsigned long long nb = __ballot(c > 0);
  int fc = 0;
  if (nb) fc = __shfl(fi, (int)__builtin_ctzll(nb));

  int s = E;
  if (s < SS) {
#pragma unroll
    for (int k = 0; k < 8; ++k) {
      unsigned ww = wv[k];
      while (ww && s < SS) {
        const int bpos = (int)__builtin_ctz(ww);
        ww &= ww - 1;
        myout[s++] = lane * 256 + k * 32 + bpos;
      }
      if (s >= SS) break;
    }
  }
  for (int s2 = total + lane; s2 < SS; s2 += 64) myout[s2] = fc;

  __syncthreads();  // idxsm complete for all 4 waves; bitmap LDS now dead

  // ---------------- Phase G: gather + group ------------------------------
  const int base = blockIdx.x * TILE;
  const int t = threadIdx.x;
  const size_t PS = (size_t)PP * SS;

  const float4* ftb = (const float4*)(featT + (size_t)b * NN * CC);
#pragma unroll
  for (int k = 0; k < 8; ++k) {
    const int u = k * 256 + t;  // [0, 2048)
    const int r = u >> 4;       // sample row 0..127
    const int q = u & 15;       // float4 within row
    const int v = idxsm[r];
    const float4 val = ftb[(size_t)v * 16 + q];
    float* dst = &smem[r * 65 + q * 4];
    dst[0] = val.x; dst[1] = val.y; dst[2] = val.z; dst[3] = val.w;
  }
  __syncthreads();

  if (t < TILE) {
    const int g = base + t;
    const int v = idxsm[t];
    const int p = (g >> 5) & (PP - 1);
    const float* xr = xyz + ((size_t)b * NN + v) * 3;
    const float* cr = new_xyz + (size_t)(b * PP + p) * 3;
    const size_t ob = (size_t)b * OUTCH * PS + ((size_t)g & (PS - 1));
    out[ob + 0 * PS] = xr[0] - cr[0];
    out[ob + 1 * PS] = xr[1] - cr[1];
    out[ob + 2 * PS] = xr[2] - cr[2];
  }

  float* ob3 = out + (size_t)b * OUTCH * PS + 3 * PS + ((size_t)base & (PS - 1));
#pragma unroll
  for (int k = 0; k < 32; ++k) {
    const int u = k * 256 + t;  // [0, 8192)
    const int c2 = u >> 7;      // channel 0..63
    const int r = u & 127;      // row 0..127
    ob3[(size_t)c2 * PS + r] = smem[r * 65 + c2];
  }
}

extern "C" void kernel_launch(void* const* d_in, const int* in_sizes, int n_in,
                              void* d_out, int out_size, void* d_ws, size_t ws_size,
                              hipStream_t stream) {
  const float* xyz = (const float*)d_in[0];
  const float* new_xyz = (const float*)d_in[1];
  const float* feat = (const float*)d_in[2];
  float* out = (float*)d_out;

  // ws layout (all live simultaneously => disjoint):
  //   [featT 8.39MB][sorted4 0.5MB][cellStart 8008B][hist 8000B][fill 8000B][done 32B]
  float* featT = (float*)d_ws;
  char* p = (char*)d_ws + (size_t)BB * NN * CC * sizeof(float);
  float4* sorted4 = (float4*)p;
  p += (size_t)BB * NN * sizeof(float4);
  int* cellStart = (int*)p;
  p += (size_t)BB * 1001 * sizeof(int);
  int* hist = (int*)p;          // contiguous zero region starts here
  int* fill = hist + BB * NCELL;
  int* done = fill + BB * NCELL;

  // D1: transpose + zero the hist/fill/done region (every call — replay-safe)
  transpose_feat_kernel<<<dim3(NN / 64, BB), 256, 0, stream>>>(feat, featT, hist);
  // D2: one-dispatch binning with resident-grid barrier
  bin_all_kernel<<<BINBLK, 256, 0, stream>>>(xyz, hist, fill, done, cellStart,
                                             sorted4);
  // D3: fused query + group
  query_group_kernel<<<(BB * PP) / 4, 256, 0, stream>>>(sorted4, cellStart,
                                                        new_xyz, xyz, featT, out);
}